// Round 1
// 866.777 us; speedup vs baseline: 1.1550x; 1.1550x over previous
//
#include <hip/hip_runtime.h>
#include <hip/hip_bf16.h>

typedef __bf16 bfv8 __attribute__((ext_vector_type(8)));
typedef float f32x4 __attribute__((ext_vector_type(4)));
typedef unsigned short u16;
typedef unsigned int u32;

#define MT 78400   // total tokens = 400*196

#define SBAR() __builtin_amdgcn_s_barrier()
#define VMCNT(n) asm volatile("s_waitcnt vmcnt(" #n ")" ::: "memory")

__device__ __forceinline__ u16 f2bf(float f) {
  u32 x = __float_as_uint(f);
  return (u16)((x + 0x7FFFu + ((x >> 16) & 1u)) >> 16);
}

__device__ __forceinline__ void gld16(const void* g, void* l) {
  __builtin_amdgcn_global_load_lds((const __attribute__((address_space(1))) void*)g,
                                   (__attribute__((address_space(3))) void*)l, 16, 0, 0);
}

// ---------------- fp32 -> bf16 convert ----------------
__global__ __launch_bounds__(256) void cvt_f32_bf16(const float* __restrict__ src,
                                                    u16* __restrict__ dst, int n8) {
  int stride = gridDim.x * 256;
  for (int i = blockIdx.x * 256 + threadIdx.x; i < n8; i += stride) {
    const float4* s = (const float4*)(src + (long)i * 8);
    float4 a = s[0], b = s[1];
    u32 p0 = f2bf(a.x) | ((u32)f2bf(a.y) << 16);
    u32 p1 = f2bf(a.z) | ((u32)f2bf(a.w) << 16);
    u32 p2 = f2bf(b.x) | ((u32)f2bf(b.y) << 16);
    u32 p3 = f2bf(b.z) | ((u32)f2bf(b.w) << 16);
    uint4 o = {p0, p1, p2, p3};
    *(uint4*)(dst + (long)i * 8) = o;
  }
}

// ================= 256x256 / BK=64 / 8-wave / 8-phase GEMM core =================
// LDS: 2 slots x (A[256][64] + B[256][64]) bf16 = 131072 B. Slot s (u16 units):
//   A at s*32768, B at s*32768+16384; half h at +h*8192; 16B chunk c at +c*8.
// Swizzle: within a 128B row, 16B slot s' = s ^ (row&7)  -> 2-way (free) ds_read_b128.
// Staged via global_load_lds with PRE-SWIZZLED global source (rule #21).
// Schedule per K-tile u (slot sl=u&1), 4 phases:
//   p0: read B(u) frags (8x b128) + A mi{0,1}; stage A(u+1) half0 -> slot sl^1
//   p1: A mi{2,3};                             stage A(u+1) half1
//   p2: A mi{4,5};                             stage B(u+2) half0 -> slot sl (B region dead since p0)
//   p3: A mi{6,7};                             stage B(u+2) half1; VMCNT(4)
//   each phase: SBAR; setprio(1); 16 MFMA; setprio(0); SBAR
// vmcnt(4) leaves only the 2 just-issued B(u+2) halves in flight -> A(u+1)/B(u+1)
// confirmed before tile u+1 reads them. Tail: k-tile index clamped to 11 (dummy
// re-stages land in dead regions; epilogue's __syncthreads drains them).

__device__ __forceinline__ void stageA(const u16* __restrict__ A, u16* SH, int sl,
                                       int m0, int kt, int h, int tid) {
#pragma unroll
  for (int i = 0; i < 2; ++i) {
    int c = tid + 512 * i;            // 0..1023
    int r = c >> 3, s = c & 7;
    int gc = s ^ (r & 7);             // inverse swizzle on global source
    int mr = m0 + h * 128 + r; if (mr > MT - 1) mr = MT - 1;
    gld16(A + mr * 768 + kt * 64 + gc * 8, SH + sl * 32768 + h * 8192 + c * 8);
  }
}

__device__ __forceinline__ void stageB(const u16* __restrict__ W, u16* SH, int sl,
                                       int n0, int kt, int h, int tid) {
#pragma unroll
  for (int i = 0; i < 2; ++i) {
    int c = tid + 512 * i;
    int r = c >> 3, s = c & 7;
    int gc = s ^ (r & 7);
    gld16(W + (n0 + h * 128 + r) * 768 + kt * 64 + gc * 8,
          SH + sl * 32768 + 16384 + h * 8192 + c * 8);
  }
}

__device__ __forceinline__ void gemm256_main(const u16* __restrict__ A, const u16* __restrict__ W,
                                             u16* SH, int m0, int n0, int tid,
                                             f32x4 (&acc)[8][4]) {
  const int lane = tid & 63;
  const int q15 = lane & 15, g = lane >> 4;
  const int wid = tid >> 6;
  const int wm = wid >> 2, wn = wid & 3;   // 2 x 4 waves; per-wave C = 128 x 64
  const int q7 = q15 & 7;
  const int x0 = (g ^ q7) << 3;            // swizzled u16 offset of ksub0 slot (x1 = x0^32)
  const int arow0 = wm * 128 + q15;
  const int brow0 = wn * 64 + q15;

  // prologue: B(0), A(0), B(1)  (6 half-tiles, 12 loads/thread)
  stageB(W, SH, 0, n0, 0, 0, tid); stageB(W, SH, 0, n0, 0, 1, tid);
  stageA(A, SH, 0, m0, 0, 0, tid); stageA(A, SH, 0, m0, 0, 1, tid);
  stageB(W, SH, 1, n0, 1, 0, tid); stageB(W, SH, 1, n0, 1, 1, tid);
  VMCNT(4);                                // B(0)+A(0) landed; B(1) may be in flight
  SBAR();

  for (int u = 0; u < 12; ++u) {
    const int sl = u & 1;
    const u16* Sa = SH + sl * 32768;
    const u16* Sb = Sa + 16384;
    const int ka = (u + 1 < 12) ? u + 1 : 11;   // clamp -> dummy re-stage at tail
    const int kb = (u + 2 < 12) ? u + 2 : 11;
    bfv8 b0[4], b1[4];
#pragma unroll
    for (int p = 0; p < 4; ++p) {
      if (p == 0) {
#pragma unroll
        for (int ni = 0; ni < 4; ++ni) {
          const u16* bp = Sb + (brow0 + ni * 16) * 64;
          b0[ni] = *(const bfv8*)(bp + x0);
          b1[ni] = *(const bfv8*)(bp + (x0 ^ 32));
        }
      }
      bfv8 a0[2], a1[2];
#pragma unroll
      for (int m2 = 0; m2 < 2; ++m2) {
        const u16* ap = Sa + (arow0 + (p * 2 + m2) * 16) * 64;
        a0[m2] = *(const bfv8*)(ap + x0);
        a1[m2] = *(const bfv8*)(ap + (x0 ^ 32));
      }
      if (p == 0)      stageA(A, SH, sl ^ 1, m0, ka, 0, tid);
      else if (p == 1) stageA(A, SH, sl ^ 1, m0, ka, 1, tid);
      else if (p == 2) stageB(W, SH, sl, n0, kb, 0, tid);
      else           { stageB(W, SH, sl, n0, kb, 1, tid); VMCNT(4); }
      SBAR();
      __builtin_amdgcn_s_setprio(1);
#pragma unroll
      for (int m2 = 0; m2 < 2; ++m2)
#pragma unroll
        for (int ni = 0; ni < 4; ++ni)
          acc[p * 2 + m2][ni] = __builtin_amdgcn_mfma_f32_16x16x32_bf16(a0[m2], b0[ni], acc[p * 2 + m2][ni], 0, 0, 0);
#pragma unroll
      for (int m2 = 0; m2 < 2; ++m2)
#pragma unroll
        for (int ni = 0; ni < 4; ++ni)
          acc[p * 2 + m2][ni] = __builtin_amdgcn_mfma_f32_16x16x32_bf16(a1[m2], b1[ni], acc[p * 2 + m2][ni], 0, 0, 0);
      __builtin_amdgcn_s_setprio(0);
      SBAR();
    }
  }
}

// ---------------- QKV GEMM: 256x256 8-phase ----------------
// grid = 307 x 9 = 2763; bijective XCD chunking (q=345, r=3).
__global__ __launch_bounds__(512, 2) void qkv_gemm(const u16* __restrict__ A, const u16* __restrict__ W,
                                                   const float* __restrict__ bias,
                                                   u16* __restrict__ Qo, u16* __restrict__ Ko,
                                                   u16* __restrict__ Vo) {
  extern __shared__ u16 SH[];
  const int tid = threadIdx.x;
  const int orig = blockIdx.x;
  const int xcd = orig & 7, ii = orig >> 3;
  const int wg = (xcd < 3 ? xcd * 346 : 1038 + (xcd - 3) * 345) + ii;
  const int mt = wg / 9, nt = wg - mt * 9;
  const int m0 = mt * 256, n0 = nt * 256;

  f32x4 acc[8][4];
#pragma unroll
  for (int i = 0; i < 8; ++i)
#pragma unroll
    for (int j = 0; j < 4; ++j) acc[i][j] = (f32x4){0.f, 0.f, 0.f, 0.f};

  gemm256_main(A, W, SH, m0, n0, tid, acc);

  const int lane = tid & 63, q15 = lane & 15, g = lane >> 4;
  const int wid = tid >> 6, wm = wid >> 2, wn = wid & 3;
  __syncthreads();                          // drains vmcnt(0) incl. dummy tail stages
  const int sel = nt / 3;                   // N-tiles 0-2 -> Q, 3-5 -> K, 6-8 -> V
  u16* dst = (sel == 0) ? Qo : (sel == 1) ? Ko : Vo;
  const int ntr = nt - sel * 3;
  u16* Cs = SH;                             // [128][264]

#pragma unroll
  for (int h = 0; h < 2; ++h) {
    if (wm == h) {
#pragma unroll
      for (int ni = 0; ni < 4; ++ni) {
        int col = wn * 64 + ni * 16 + q15;
        float bb = bias[n0 + col];
#pragma unroll
        for (int mi = 0; mi < 8; ++mi)
#pragma unroll
          for (int r = 0; r < 4; ++r)
            Cs[(mi * 16 + g * 4 + r) * 264 + col] = f2bf(acc[mi][ni][r] + bb);
      }
    }
    __syncthreads();
#pragma unroll
    for (int j = 0; j < 8; ++j) {
      int idx = tid + 512 * j;
      int row = idx >> 5, cc = idx & 31;
      int m = m0 + h * 128 + row;
      if (m < MT) {
        int b = m / 196, s = m - b * 196;
        int nh = ntr * 4 + (cc >> 3);
        int hd0 = (cc & 7) * 8;
        uint4 v = *(const uint4*)(Cs + row * 264 + cc * 8);
        *(uint4*)(dst + (long)b * 150528 + (long)s * 64 + nh * 12544 + hd0) = v;
      }
    }
    if (h == 0) __syncthreads();
  }
}

// ---------------- Proj GEMM: 256x256 8-phase, f32 output ----------------
// grid = 307 x 3 = 921; bijective XCD chunking (q=115, r=1).
__global__ __launch_bounds__(512, 2) void proj_gemm(const u16* __restrict__ A, const u16* __restrict__ W,
                                                    const float* __restrict__ bias,
                                                    float* __restrict__ out) {
  extern __shared__ u16 SH[];
  const int tid = threadIdx.x;
  const int orig = blockIdx.x;
  const int xcd = orig & 7, ii = orig >> 3;
  const int wg = (xcd < 1 ? xcd * 116 : 116 + (xcd - 1) * 115) + ii;
  const int mt = wg / 3, nt = wg - mt * 3;
  const int m0 = mt * 256, n0 = nt * 256;

  f32x4 acc[8][4];
#pragma unroll
  for (int i = 0; i < 8; ++i)
#pragma unroll
    for (int j = 0; j < 4; ++j) acc[i][j] = (f32x4){0.f, 0.f, 0.f, 0.f};

  gemm256_main(A, W, SH, m0, n0, tid, acc);

  const int lane = tid & 63, q15 = lane & 15, g = lane >> 4;
  const int wid = tid >> 6, wm = wid >> 2, wn = wid & 3;

#pragma unroll
  for (int ni = 0; ni < 4; ++ni) {
    int n = n0 + wn * 64 + ni * 16 + q15;
    float bb = bias[n];
#pragma unroll
    for (int mi = 0; mi < 8; ++mi)
#pragma unroll
      for (int r = 0; r < 4; ++r) {
        int m = m0 + wm * 128 + mi * 16 + g * 4 + r;
        if (m < MT) out[(long)m * 768 + n] = acc[mi][ni][r] + bb;
      }
  }
}

// ---------------- fused rel-pos attention, one block per (b,nh), 8 waves ----------------
#define KLDS_OFF 0
#define INDK_OFF 29952
#define VT_OFF   46592
#define TH_OFF   79360
#define TW_OFF   83248
#define AW_OFF   87136
#define P_OFF    97376
#define SMEM_SZ  156768

__global__ __launch_bounds__(512, 2) void attn_kernel(const u16* __restrict__ Q, const u16* __restrict__ K,
                                                      const u16* __restrict__ V,
                                                      const float* __restrict__ rph, const float* __restrict__ rpw,
                                                      u16* __restrict__ AO) {
  extern __shared__ char smem[];
  u16* Klds = (u16*)(smem + KLDS_OFF);
  u16* IndK = (u16*)(smem + INDK_OFF);
  u16* VT = (u16*)(smem + VT_OFF);
  u16* TH = (u16*)(smem + TH_OFF);
  u16* TW = (u16*)(smem + TW_OFF);
  const int tid = threadIdx.x, lane = tid & 63, wid = tid >> 6;
  const int q15 = lane & 15, g = lane >> 4;
  const int bnh = blockIdx.x;
  const int b = bnh / 12, nh = bnh - b * 12;
  const u16* Qg = Q + bnh * 12544;
  const u16* Kg = K + bnh * 12544;
  const u16* Vg = V + bnh * 12544;
  u16* Pw = (u16*)(smem + P_OFF) + wid * 16 * 232;
  u16* AWw = (u16*)(smem + AW_OFF) + wid * 16 * 40;

  for (int c = tid; c < 1764; c += 512) {
    int krow = c / 9, part = c - krow * 9;
    gld16(Kg + krow * 64 + part * 8, Klds + c * 8);
  }
  for (int i = tid; i < 208 * 40; i += 512) {
    int k = i / 40, j = i - (i / 40) * 40;
    int hk = k / 14, wk = k - hk * 14;
    IndK[i] = (j == hk || j == 16 + wk) ? 0x3F80 : 0;
  }
  for (int idx = tid; idx < 1792; idx += 512) {
    int k = idx >> 3, nb = idx & 7;
    u32 w0 = 0, w1 = 0, w2 = 0, w3 = 0;
    if (k < 196) {
      uint4 t = *(const uint4*)(Vg + k * 64 + nb * 8);
      w0 = t.x; w1 = t.y; w2 = t.z; w3 = t.w;
    }
    u32 wv[4] = {w0, w1, w2, w3};
#pragma unroll
    for (int j = 0; j < 8; j++) {
      int n = nb * 8 + j;
      u16 val = (u16)(wv[j >> 1] >> ((j & 1) * 16));
      int blk = (k >> 3) ^ (n & 7) ^ (n >> 3);
      VT[n * 256 + blk * 8 + (k & 7)] = val;
    }
  }
  for (int i = tid; i < 27 * 64; i += 512) {
    int r = i >> 6, cc = i & 63;
    TH[r * 72 + cc] = f2bf(rph[i]);
    TW[r * 72 + cc] = f2bf(rpw[i]);
  }
  for (int i = lane; i < 16 * 24; i += 64) Pw[(i / 24) * 232 + 208 + (i % 24)] = 0;
  __syncthreads();

  const f32x4 zero = {0.f, 0.f, 0.f, 0.f};
  for (int qt = wid; qt < 13; qt += 8) {
    const int q0 = qt * 16;
    int qrow = q0 + q15; if (qrow > 195) qrow = 195;
    bfv8 qf0 = *(const bfv8*)(Qg + qrow * 64 + g * 8);
    bfv8 qf1 = *(const bfv8*)(Qg + qrow * 64 + 32 + g * 8);

    int hq0 = q0 / 14, hq1 = (q0 + 15) / 14;
    int rha = hq0 + 13 - q15; rha = rha < 0 ? 0 : (rha > 26 ? 26 : rha);
    int rhb = hq1 + 13 - q15; rhb = rhb < 0 ? 0 : (rhb > 26 ? 26 : rhb);
    int rwa = q15;
    int rwb = 16 + q15; if (rwb > 26) rwb = 26;
    f32x4 c0h = zero, c1h = zero, c0w = zero, c1w = zero;
    {
      bfv8 t0 = *(const bfv8*)(TH + rha * 72 + g * 8);
      bfv8 t1 = *(const bfv8*)(TH + rha * 72 + 32 + g * 8);
      c0h = __builtin_amdgcn_mfma_f32_16x16x32_bf16(qf0, t0, c0h, 0, 0, 0);
      c0h = __builtin_amdgcn_mfma_f32_16x16x32_bf16(qf1, t1, c0h, 0, 0, 0);
      bfv8 t2 = *(const bfv8*)(TH + rhb * 72 + g * 8);
      bfv8 t3 = *(const bfv8*)(TH + rhb * 72 + 32 + g * 8);
      c1h = __builtin_amdgcn_mfma_f32_16x16x32_bf16(qf0, t2, c1h, 0, 0, 0);
      c1h = __builtin_amdgcn_mfma_f32_16x16x32_bf16(qf1, t3, c1h, 0, 0, 0);
      bfv8 u0 = *(const bfv8*)(TW + rwa * 72 + g * 8);
      bfv8 u1 = *(const bfv8*)(TW + rwa * 72 + 32 + g * 8);
      c0w = __builtin_amdgcn_mfma_f32_16x16x32_bf16(qf0, u0, c0w, 0, 0, 0);
      c0w = __builtin_amdgcn_mfma_f32_16x16x32_bf16(qf1, u1, c0w, 0, 0, 0);
      bfv8 u2 = *(const bfv8*)(TW + rwb * 72 + g * 8);
      bfv8 u3 = *(const bfv8*)(TW + rwb * 72 + 32 + g * 8);
      c1w = __builtin_amdgcn_mfma_f32_16x16x32_bf16(qf0, u2, c1w, 0, 0, 0);
      c1w = __builtin_amdgcn_mfma_f32_16x16x32_bf16(qf1, u3, c1w, 0, 0, 0);
    }

#pragma unroll
    for (int r = 0; r < 4; r++) {
      int row = g * 4 + r;
      int qq = q0 + row;
      int hqr = qq / 14;
      int wq_r = qq - hqr * 14;
      if (q15 < 10) AWw[row * 40 + 30 + q15] = 0;
      float rh = ((hqr == hq1) ? c1h[r] : c0h[r]) * 8.0f;
      AWw[row * 40 + q15] = (q15 <= 13) ? f2bf(rh) : (u16)0;
      int w0p = wq_r + 13 - q15;
      if (w0p >= 0 && w0p <= 13) AWw[row * 40 + 16 + w0p] = f2bf(c0w[r] * 8.0f);
      int w1p = wq_r - 3 - q15;
      if (w1p >= 0 && w1p <= 13) AWw[row * 40 + 16 + w1p] = f2bf(c1w[r] * 8.0f);
    }
    bfv8 qaug = *(const bfv8*)(AWw + q15 * 40 + g * 8);

    float den[4] = {0.f, 0.f, 0.f, 0.f};
#pragma unroll
    for (int t = 0; t < 13; t++) {
      bfv8 kb0 = *(const bfv8*)(Klds + (t * 16 + q15) * 72 + g * 8);
      bfv8 kb1 = *(const bfv8*)(Klds + (t * 16 + q15) * 72 + 32 + g * 8);
      bfv8 ib = *(const bfv8*)(IndK + (t * 16 + q15) * 40 + g * 8);
      __builtin_amdgcn_s_setprio(1);
      f32x4 a0 = __builtin_amdgcn_mfma_f32_16x16x32_bf16(qaug, ib, zero, 0, 0, 0);
      f32x4 a1 = __builtin_amdgcn_mfma_f32_16x16x32_bf16(qf0, kb0, a0, 0, 0, 0);
      f32x4 st = __builtin_amdgcn_mfma_f32_16x16x32_bf16(qf1, kb1, a1, 0, 0, 0);
      __builtin_amdgcn_s_setprio(0);
#pragma unroll
      for (int r = 0; r < 4; r++) {
        float v = st[r] * 0.125f - 4.0f;
        float p = (t == 12 && q15 >= 4) ? 0.f : exp2f(v * 1.44269504f);
        den[r] += p;
        Pw[(g * 4 + r) * 232 + t * 16 + q15] = f2bf(p);
      }
    }
#pragma unroll
    for (int r = 0; r < 4; r++) {
      den[r] += __shfl_xor(den[r], 1);
      den[r] += __shfl_xor(den[r], 2);
      den[r] += __shfl_xor(den[r], 4);
      den[r] += __shfl_xor(den[r], 8);
    }

    f32x4 o[4] = {zero, zero, zero, zero};
    __builtin_amdgcn_s_setprio(1);
#pragma unroll
    for (int ks = 0; ks < 7; ks++) {
      bfv8 pa = *(const bfv8*)(Pw + q15 * 232 + ks * 32 + g * 8);
#pragma unroll
      for (int nt = 0; nt < 4; nt++) {
        int n = nt * 16 + q15;
        int blk = ((ks * 4 + g) ^ (n & 7) ^ (n >> 3));
        bfv8 vb = *(const bfv8*)(VT + n * 256 + blk * 8);
        o[nt] = __builtin_amdgcn_mfma_f32_16x16x32_bf16(pa, vb, o[nt], 0, 0, 0);
      }
    }
    __builtin_amdgcn_s_setprio(0);

    float inv[4];
#pragma unroll
    for (int r = 0; r < 4; r++) inv[r] = 1.0f / den[r];
#pragma unroll
    for (int nt = 0; nt < 4; nt++)
#pragma unroll
      for (int r = 0; r < 4; r++) {
        int s_ = q0 + g * 4 + r;
        if (s_ < 196) AO[((long)(b * 196 + s_)) * 768 + nh * 64 + nt * 16 + q15] = f2bf(o[nt][r] * inv[r]);
      }
  }
}

// ---------------- launch ----------------
#define GEMM_LDS 131072

extern "C" void kernel_launch(void* const* d_in, const int* in_sizes, int n_in,
                              void* d_out, int out_size, void* d_ws, size_t ws_size,
                              hipStream_t stream) {
  const float* hs = (const float*)d_in[0];
  const float* qkvw = (const float*)d_in[1];
  const float* qkvb = (const float*)d_in[2];
  const float* projw = (const float*)d_in[3];
  const float* projb = (const float*)d_in[4];
  const float* rph = (const float*)d_in[5];
  const float* rpw = (const float*)d_in[6];

  char* ws = (char*)d_ws;
  u16* Xb = (u16*)ws;                        // 120,422,400 B (reused as attention output)
  u16* Wq = (u16*)(ws + 120422400);          // 3,538,944 B
  u16* Wp = (u16*)(ws + 123961344);          // 1,179,648 B
  u16* Qb = (u16*)(ws + 125140992);          // 120,422,400 B
  u16* Kb = (u16*)(ws + 245563392);          // 120,422,400 B
  u16* Vb = (u16*)(ws + 365985792);          // 120,422,400 B
  u16* AO = Xb;

  cvt_f32_bf16<<<2048, 256, 0, stream>>>(hs, Xb, 7526400);
  cvt_f32_bf16<<<864, 256, 0, stream>>>(qkvw, Wq, 221184);
  cvt_f32_bf16<<<288, 256, 0, stream>>>(projw, Wp, 73728);

  hipFuncSetAttribute((const void*)qkv_gemm, hipFuncAttributeMaxDynamicSharedMemorySize, GEMM_LDS);
  qkv_gemm<<<2763, 512, GEMM_LDS, stream>>>(Xb, Wq, qkvb, Qb, Kb, Vb);

  hipFuncSetAttribute((const void*)attn_kernel, hipFuncAttributeMaxDynamicSharedMemorySize, SMEM_SZ);
  attn_kernel<<<4800, 512, SMEM_SZ, stream>>>(Qb, Kb, Vb, rph, rpw, AO);

  hipFuncSetAttribute((const void*)proj_gemm, hipFuncAttributeMaxDynamicSharedMemorySize, GEMM_LDS);
  proj_gemm<<<921, 512, GEMM_LDS, stream>>>(AO, Wp, projb, (float*)d_out);
}

// Round 2
// 845.451 us; speedup vs baseline: 1.1842x; 1.0252x over previous
//
#include <hip/hip_runtime.h>
#include <hip/hip_bf16.h>

typedef __bf16 bfv8 __attribute__((ext_vector_type(8)));
typedef float f32x4 __attribute__((ext_vector_type(4)));
typedef unsigned short u16;
typedef unsigned int u32;

#define MT 78400   // total tokens = 400*196

#define SBAR() __builtin_amdgcn_s_barrier()
#define VMCNT(n) asm volatile("s_waitcnt vmcnt(" #n ")" ::: "memory")

__device__ __forceinline__ u16 f2bf(float f) {
  u32 x = __float_as_uint(f);
  return (u16)((x + 0x7FFFu + ((x >> 16) & 1u)) >> 16);
}

__device__ __forceinline__ void gld16(const void* g, void* l) {
  __builtin_amdgcn_global_load_lds((const __attribute__((address_space(1))) void*)g,
                                   (__attribute__((address_space(3))) void*)l, 16, 0, 0);
}

// ---------------- fp32 -> bf16 convert ----------------
__global__ __launch_bounds__(256) void cvt_f32_bf16(const float* __restrict__ src,
                                                    u16* __restrict__ dst, int n8) {
  int stride = gridDim.x * 256;
  for (int i = blockIdx.x * 256 + threadIdx.x; i < n8; i += stride) {
    const float4* s = (const float4*)(src + (long)i * 8);
    float4 a = s[0], b = s[1];
    u32 p0 = f2bf(a.x) | ((u32)f2bf(a.y) << 16);
    u32 p1 = f2bf(a.z) | ((u32)f2bf(a.w) << 16);
    u32 p2 = f2bf(b.x) | ((u32)f2bf(b.y) << 16);
    u32 p3 = f2bf(b.z) | ((u32)f2bf(b.w) << 16);
    uint4 o = {p0, p1, p2, p3};
    *(uint4*)(dst + (long)i * 8) = o;
  }
}

// ================= 256x256 / BK=64 / 8-wave GEMM core, reg-double-buffered =================
// LDS: 2 slots x (A[256][64] + B[256][64]) bf16 = 131072 B. Slot s (u16 units):
//   A at s*32768, B at s*32768+16384; half h at +h*8192; 16B chunk c at +c*8.
// Swizzle: within a 128B row, 16B slot s' = s ^ (row&7); staged via pre-swizzled
// global source (rule #21), read with same XOR (measured 0 conflicts, round 1).
// Schedule per K-tile u (slot sl=u&1), phase q ∈ 0..3, fragment sets X/Y alternate:
//   q: MFMA(quadrant q, set cur) ; [vmcnt(4) if q==3] ; s_barrier ;
//      ds_read(quadrant q+1 -> set next; +next-tile B at q==3) ; stage 1 half-tile
// Stage map: q0: A(u+1)h1 -> slot sl^1 | q1: B(u+2)h0 -> slot sl (B dead after q3-prev reads)
//            q2: B(u+2)h1 | q3: A(u+2)h0 -> slot sl (A dead: all quadrants read by q2-trailing)
// vmcnt(4)@q3 completes B(u+1)+A(u+1) (read right after the barrier), leaves B(u+2) in
// flight. Trailing reads overlap the matrix-pipe drain of the just-issued MFMAs.
// Tail: k-tile index clamped to 11 (dummy re-stages land in dead regions).

__device__ __forceinline__ void stageA(const u16* __restrict__ A, u16* SH, int sl,
                                       int m0, int kt, int h, int tid) {
#pragma unroll
  for (int i = 0; i < 2; ++i) {
    int c = tid + 512 * i;            // 0..1023
    int r = c >> 3, s = c & 7;
    int gc = s ^ (r & 7);             // inverse swizzle on global source
    int mr = m0 + h * 128 + r; if (mr > MT - 1) mr = MT - 1;
    gld16(A + mr * 768 + kt * 64 + gc * 8, SH + sl * 32768 + h * 8192 + c * 8);
  }
}

__device__ __forceinline__ void stageB(const u16* __restrict__ W, u16* SH, int sl,
                                       int n0, int kt, int h, int tid) {
#pragma unroll
  for (int i = 0; i < 2; ++i) {
    int c = tid + 512 * i;
    int r = c >> 3, s = c & 7;
    int gc = s ^ (r & 7);
    gld16(W + (n0 + h * 128 + r) * 768 + kt * 64 + gc * 8,
          SH + sl * 32768 + 16384 + h * 8192 + c * 8);
  }
}

__device__ __forceinline__ void gemm256_main(const u16* __restrict__ A, const u16* __restrict__ W,
                                             u16* SH, int m0, int n0, int tid,
                                             f32x4 (&acc)[8][4]) {
  const int lane = tid & 63;
  const int q15 = lane & 15, g = lane >> 4;
  const int wid = tid >> 6;
  const int wm = wid >> 2, wn = wid & 3;   // 2 x 4 waves; per-wave C = 128 x 64
  const int x0 = (g ^ (q15 & 7)) << 3;     // swizzled u16 offset of ksub0 (ksub1 = x0^32)
  const int arow0 = wm * 128 + q15;
  const int brow0 = wn * 64 + q15;

  bfv8 b0[4], b1[4];
  bfv8 aX0[2], aX1[2], aY0[2], aY1[2];

  // prologue stages: B0h0,B0h1,A0h0,A0h1,B1h0,B1h1,A1h0 (14 loads)
  stageB(W, SH, 0, n0, 0, 0, tid); stageB(W, SH, 0, n0, 0, 1, tid);
  stageA(A, SH, 0, m0, 0, 0, tid); stageA(A, SH, 0, m0, 0, 1, tid);
  stageB(W, SH, 1, n0, 1, 0, tid); stageB(W, SH, 1, n0, 1, 1, tid);
  stageA(A, SH, 1, m0, 1, 0, tid);
  VMCNT(4);                                // B0,A0,B1h0 landed; A1h0,B1h1 in flight
  SBAR();
  {
    const u16* Sb = SH + 16384;            // B(0)
#pragma unroll
    for (int ni = 0; ni < 4; ++ni) {
      const u16* bp = Sb + (brow0 + ni * 16) * 64;
      b0[ni] = *(const bfv8*)(bp + x0);
      b1[ni] = *(const bfv8*)(bp + (x0 ^ 32));
    }
#pragma unroll
    for (int m2 = 0; m2 < 2; ++m2) {       // A(0) quadrant 0 -> set X
      const u16* ap = SH + (arow0 + m2 * 16) * 64;
      aX0[m2] = *(const bfv8*)(ap + x0);
      aX1[m2] = *(const bfv8*)(ap + (x0 ^ 32));
    }
  }

  for (int u = 0; u < 12; ++u) {
    const int sl = u & 1;
    const u16* Sa = SH + sl * 32768;
    const u16* San = SH + (sl ^ 1) * 32768;
    const u16* Sbn = San + 16384;
    const int kn1 = (u + 1 < 12) ? u + 1 : 11;
    const int kn2 = (u + 2 < 12) ? u + 2 : 11;

    // ---- q0: MFMA quad0 (X) ; barrier ; read quad1->Y ; stage A(u+1)h1 ----
    __builtin_amdgcn_s_setprio(1);
#pragma unroll
    for (int m2 = 0; m2 < 2; ++m2)
#pragma unroll
      for (int ni = 0; ni < 4; ++ni)
        acc[m2][ni] = __builtin_amdgcn_mfma_f32_16x16x32_bf16(aX0[m2], b0[ni], acc[m2][ni], 0, 0, 0);
#pragma unroll
    for (int m2 = 0; m2 < 2; ++m2)
#pragma unroll
      for (int ni = 0; ni < 4; ++ni)
        acc[m2][ni] = __builtin_amdgcn_mfma_f32_16x16x32_bf16(aX1[m2], b1[ni], acc[m2][ni], 0, 0, 0);
    __builtin_amdgcn_s_setprio(0);
    SBAR();
#pragma unroll
    for (int m2 = 0; m2 < 2; ++m2) {
      const u16* ap = Sa + (arow0 + (2 + m2) * 16) * 64;
      aY0[m2] = *(const bfv8*)(ap + x0);
      aY1[m2] = *(const bfv8*)(ap + (x0 ^ 32));
    }
    stageA(A, SH, sl ^ 1, m0, kn1, 1, tid);

    // ---- q1: MFMA quad1 (Y) ; barrier ; read quad2->X ; stage B(u+2)h0 ----
    __builtin_amdgcn_s_setprio(1);
#pragma unroll
    for (int m2 = 0; m2 < 2; ++m2)
#pragma unroll
      for (int ni = 0; ni < 4; ++ni)
        acc[2 + m2][ni] = __builtin_amdgcn_mfma_f32_16x16x32_bf16(aY0[m2], b0[ni], acc[2 + m2][ni], 0, 0, 0);
#pragma unroll
    for (int m2 = 0; m2 < 2; ++m2)
#pragma unroll
      for (int ni = 0; ni < 4; ++ni)
        acc[2 + m2][ni] = __builtin_amdgcn_mfma_f32_16x16x32_bf16(aY1[m2], b1[ni], acc[2 + m2][ni], 0, 0, 0);
    __builtin_amdgcn_s_setprio(0);
    SBAR();
#pragma unroll
    for (int m2 = 0; m2 < 2; ++m2) {
      const u16* ap = Sa + (arow0 + (4 + m2) * 16) * 64;
      aX0[m2] = *(const bfv8*)(ap + x0);
      aX1[m2] = *(const bfv8*)(ap + (x0 ^ 32));
    }
    stageB(W, SH, sl, n0, kn2, 0, tid);

    // ---- q2: MFMA quad2 (X) ; barrier ; read quad3->Y ; stage B(u+2)h1 ----
    __builtin_amdgcn_s_setprio(1);
#pragma unroll
    for (int m2 = 0; m2 < 2; ++m2)
#pragma unroll
      for (int ni = 0; ni < 4; ++ni)
        acc[4 + m2][ni] = __builtin_amdgcn_mfma_f32_16x16x32_bf16(aX0[m2], b0[ni], acc[4 + m2][ni], 0, 0, 0);
#pragma unroll
    for (int m2 = 0; m2 < 2; ++m2)
#pragma unroll
      for (int ni = 0; ni < 4; ++ni)
        acc[4 + m2][ni] = __builtin_amdgcn_mfma_f32_16x16x32_bf16(aX1[m2], b1[ni], acc[4 + m2][ni], 0, 0, 0);
    __builtin_amdgcn_s_setprio(0);
    SBAR();
#pragma unroll
    for (int m2 = 0; m2 < 2; ++m2) {
      const u16* ap = Sa + (arow0 + (6 + m2) * 16) * 64;
      aY0[m2] = *(const bfv8*)(ap + x0);
      aY1[m2] = *(const bfv8*)(ap + (x0 ^ 32));
    }
    stageB(W, SH, sl, n0, kn2, 1, tid);

    // ---- q3: MFMA quad3 (Y) ; vmcnt(4) ; barrier ; read nextB+quad0->X ; stage A(u+2)h0 ----
    __builtin_amdgcn_s_setprio(1);
#pragma unroll
    for (int m2 = 0; m2 < 2; ++m2)
#pragma unroll
      for (int ni = 0; ni < 4; ++ni)
        acc[6 + m2][ni] = __builtin_amdgcn_mfma_f32_16x16x32_bf16(aY0[m2], b0[ni], acc[6 + m2][ni], 0, 0, 0);
#pragma unroll
    for (int m2 = 0; m2 < 2; ++m2)
#pragma unroll
      for (int ni = 0; ni < 4; ++ni)
        acc[6 + m2][ni] = __builtin_amdgcn_mfma_f32_16x16x32_bf16(aY1[m2], b1[ni], acc[6 + m2][ni], 0, 0, 0);
    __builtin_amdgcn_s_setprio(0);
    VMCNT(4);                    // completes B(u+1)+A(u+1); leaves B(u+2) in flight
    SBAR();
    if (u < 11) {
#pragma unroll
      for (int ni = 0; ni < 4; ++ni) {
        const u16* bp = Sbn + (brow0 + ni * 16) * 64;
        b0[ni] = *(const bfv8*)(bp + x0);
        b1[ni] = *(const bfv8*)(bp + (x0 ^ 32));
      }
#pragma unroll
      for (int m2 = 0; m2 < 2; ++m2) {
        const u16* ap = San + (arow0 + m2 * 16) * 64;
        aX0[m2] = *(const bfv8*)(ap + x0);
        aX1[m2] = *(const bfv8*)(ap + (x0 ^ 32));
      }
    }
    stageA(A, SH, sl, m0, kn2, 0, tid);
  }
  VMCNT(0);                      // drain dummy tail stages before LDS reuse / exit
}

// ---------------- QKV GEMM: 256x256 ----------------
// grid = 307 x 9 = 2763; bijective XCD chunking (q=345, r=3).
__global__ __launch_bounds__(512, 2) void qkv_gemm(const u16* __restrict__ A, const u16* __restrict__ W,
                                                   const float* __restrict__ bias,
                                                   u16* __restrict__ Qo, u16* __restrict__ Ko,
                                                   u16* __restrict__ Vo) {
  extern __shared__ u16 SH[];
  const int tid = threadIdx.x;
  const int orig = blockIdx.x;
  const int xcd = orig & 7, ii = orig >> 3;
  const int wg = (xcd < 3 ? xcd * 346 : 1038 + (xcd - 3) * 345) + ii;
  const int mt = wg / 9, nt = wg - mt * 9;
  const int m0 = mt * 256, n0 = nt * 256;

  f32x4 acc[8][4];
#pragma unroll
  for (int i = 0; i < 8; ++i)
#pragma unroll
    for (int j = 0; j < 4; ++j) acc[i][j] = (f32x4){0.f, 0.f, 0.f, 0.f};

  gemm256_main(A, W, SH, m0, n0, tid, acc);

  const int lane = tid & 63, q15 = lane & 15, g = lane >> 4;
  const int wid = tid >> 6, wm = wid >> 2, wn = wid & 3;
  __syncthreads();                          // all waves done with SH
  const int sel = nt / 3;                   // N-tiles 0-2 -> Q, 3-5 -> K, 6-8 -> V
  u16* dst = (sel == 0) ? Qo : (sel == 1) ? Ko : Vo;
  const int ntr = nt - sel * 3;
  u16* Cs = SH;                             // [128][264]

#pragma unroll
  for (int h = 0; h < 2; ++h) {
    if (wm == h) {
#pragma unroll
      for (int ni = 0; ni < 4; ++ni) {
        int col = wn * 64 + ni * 16 + q15;
        float bb = bias[n0 + col];
#pragma unroll
        for (int mi = 0; mi < 8; ++mi)
#pragma unroll
          for (int r = 0; r < 4; ++r)
            Cs[(mi * 16 + g * 4 + r) * 264 + col] = f2bf(acc[mi][ni][r] + bb);
      }
    }
    __syncthreads();
#pragma unroll
    for (int j = 0; j < 8; ++j) {
      int idx = tid + 512 * j;
      int row = idx >> 5, cc = idx & 31;
      int m = m0 + h * 128 + row;
      if (m < MT) {
        int b = m / 196, s = m - b * 196;
        int nh = ntr * 4 + (cc >> 3);
        int hd0 = (cc & 7) * 8;
        uint4 v = *(const uint4*)(Cs + row * 264 + cc * 8);
        *(uint4*)(dst + (long)b * 150528 + (long)s * 64 + nh * 12544 + hd0) = v;
      }
    }
    if (h == 0) __syncthreads();
  }
}

// ---------------- Proj GEMM: 256x256, f32 output ----------------
// grid = 307 x 3 = 921; bijective XCD chunking (q=115, r=1).
__global__ __launch_bounds__(512, 2) void proj_gemm(const u16* __restrict__ A, const u16* __restrict__ W,
                                                    const float* __restrict__ bias,
                                                    float* __restrict__ out) {
  extern __shared__ u16 SH[];
  const int tid = threadIdx.x;
  const int orig = blockIdx.x;
  const int xcd = orig & 7, ii = orig >> 3;
  const int wg = (xcd < 1 ? xcd * 116 : 116 + (xcd - 1) * 115) + ii;
  const int mt = wg / 3, nt = wg - mt * 3;
  const int m0 = mt * 256, n0 = nt * 256;

  f32x4 acc[8][4];
#pragma unroll
  for (int i = 0; i < 8; ++i)
#pragma unroll
    for (int j = 0; j < 4; ++j) acc[i][j] = (f32x4){0.f, 0.f, 0.f, 0.f};

  gemm256_main(A, W, SH, m0, n0, tid, acc);

  const int lane = tid & 63, q15 = lane & 15, g = lane >> 4;
  const int wid = tid >> 6, wm = wid >> 2, wn = wid & 3;

#pragma unroll
  for (int ni = 0; ni < 4; ++ni) {
    int n = n0 + wn * 64 + ni * 16 + q15;
    float bb = bias[n];
#pragma unroll
    for (int mi = 0; mi < 8; ++mi)
#pragma unroll
      for (int r = 0; r < 4; ++r) {
        int m = m0 + wm * 128 + mi * 16 + g * 4 + r;
        if (m < MT) out[(long)m * 768 + n] = acc[mi][ni][r] + bb;
      }
  }
}

// ---------------- fused rel-pos attention, one block per (b,nh), 8 waves ----------------
// K now stored stride-64 with XOR-chunk swizzle (chunk ^= row&7), staged via
// pre-swizzled global source; read offsets loop-invariant (16 | row stride).
#define KLDS_OFF 0          // 208*64*2   = 26624
#define INDK_OFF 26624      // 208*40*2   = 16640
#define VT_OFF   43264      // 64*256*2   = 32768
#define TH_OFF   76032      // 27*72*2    = 3888
#define TW_OFF   79920      // 3888
#define AW_OFF   83808      // 8*16*40*2  = 10240
#define P_OFF    94048      // 8*16*232*2 = 59392
#define SMEM_SZ  153440

__global__ __launch_bounds__(512, 2) void attn_kernel(const u16* __restrict__ Q, const u16* __restrict__ K,
                                                      const u16* __restrict__ V,
                                                      const float* __restrict__ rph, const float* __restrict__ rpw,
                                                      u16* __restrict__ AO) {
  extern __shared__ char smem[];
  u16* Klds = (u16*)(smem + KLDS_OFF);
  u16* IndK = (u16*)(smem + INDK_OFF);
  u16* VT = (u16*)(smem + VT_OFF);
  u16* TH = (u16*)(smem + TH_OFF);
  u16* TW = (u16*)(smem + TW_OFF);
  const int tid = threadIdx.x, lane = tid & 63, wid = tid >> 6;
  const int q15 = lane & 15, g = lane >> 4;
  const int bnh = blockIdx.x;
  const int b = bnh / 12, nh = bnh - b * 12;
  const u16* Qg = Q + bnh * 12544;
  const u16* Kg = K + bnh * 12544;
  const u16* Vg = V + bnh * 12544;
  u16* Pw = (u16*)(smem + P_OFF) + wid * 16 * 232;
  u16* AWw = (u16*)(smem + AW_OFF) + wid * 16 * 40;

  // stage K rows 0..195, stride 64, chunk-XOR swizzle via pre-swizzled source
  for (int c = tid; c < 1568; c += 512) {
    int krow = c >> 3, part = c & 7;
    gld16(Kg + krow * 64 + ((part ^ (krow & 7)) << 3), Klds + c * 8);
  }
  // static indicator block: one-hot (bf16 1.0 = 0x3F80) at hk and 16+wk
  for (int i = tid; i < 208 * 40; i += 512) {
    int k = i / 40, j = i - (i / 40) * 40;
    int hk = k / 14, wk = k - hk * 14;
    IndK[i] = (j == hk || j == 16 + wk) ? 0x3F80 : 0;
  }
  // stage V transposed + swizzled; zero-pad k>=196
  for (int idx = tid; idx < 1792; idx += 512) {
    int k = idx >> 3, nb = idx & 7;
    u32 w0 = 0, w1 = 0, w2 = 0, w3 = 0;
    if (k < 196) {
      uint4 t = *(const uint4*)(Vg + k * 64 + nb * 8);
      w0 = t.x; w1 = t.y; w2 = t.z; w3 = t.w;
    }
    u32 wv[4] = {w0, w1, w2, w3};
#pragma unroll
    for (int j = 0; j < 8; j++) {
      int n = nb * 8 + j;
      u16 val = (u16)(wv[j >> 1] >> ((j & 1) * 16));
      int blk = (k >> 3) ^ (n & 7) ^ (n >> 3);
      VT[n * 256 + blk * 8 + (k & 7)] = val;
    }
  }
  // stage rel-pos tables as bf16
  for (int i = tid; i < 27 * 64; i += 512) {
    int r = i >> 6, cc = i & 63;
    TH[r * 72 + cc] = f2bf(rph[i]);
    TW[r * 72 + cc] = f2bf(rpw[i]);
  }
  // zero own wave's P pad columns [208..231]
  for (int i = lane; i < 16 * 24; i += 64) Pw[(i / 24) * 232 + 208 + (i % 24)] = 0;
  __syncthreads();

  const int ksw = q15 & 7;
  const int ko0 = (g ^ ksw) << 3;          // swizzled chunk offsets for K reads
  const int ko1 = ((g + 4) ^ ksw) << 3;

  const f32x4 zero = {0.f, 0.f, 0.f, 0.f};
  for (int qt = wid; qt < 13; qt += 8) {
    const int q0 = qt * 16;
    int qrow = q0 + q15; if (qrow > 195) qrow = 195;
    bfv8 qf0 = *(const bfv8*)(Qg + qrow * 64 + g * 8);
    bfv8 qf1 = *(const bfv8*)(Qg + qrow * 64 + 32 + g * 8);

    // rel_h (two hq variants) and rel_w over d = wq-wk+13 (two d-tiles), via MFMA
    int hq0 = q0 / 14, hq1 = (q0 + 15) / 14;
    int rha = hq0 + 13 - q15; rha = rha < 0 ? 0 : (rha > 26 ? 26 : rha);
    int rhb = hq1 + 13 - q15; rhb = rhb < 0 ? 0 : (rhb > 26 ? 26 : rhb);
    int rwa = q15;
    int rwb = 16 + q15; if (rwb > 26) rwb = 26;
    f32x4 c0h = zero, c1h = zero, c0w = zero, c1w = zero;
    {
      bfv8 t0 = *(const bfv8*)(TH + rha * 72 + g * 8);
      bfv8 t1 = *(const bfv8*)(TH + rha * 72 + 32 + g * 8);
      c0h = __builtin_amdgcn_mfma_f32_16x16x32_bf16(qf0, t0, c0h, 0, 0, 0);
      c0h = __builtin_amdgcn_mfma_f32_16x16x32_bf16(qf1, t1, c0h, 0, 0, 0);
      bfv8 t2 = *(const bfv8*)(TH + rhb * 72 + g * 8);
      bfv8 t3 = *(const bfv8*)(TH + rhb * 72 + 32 + g * 8);
      c1h = __builtin_amdgcn_mfma_f32_16x16x32_bf16(qf0, t2, c1h, 0, 0, 0);
      c1h = __builtin_amdgcn_mfma_f32_16x16x32_bf16(qf1, t3, c1h, 0, 0, 0);
      bfv8 u0 = *(const bfv8*)(TW + rwa * 72 + g * 8);
      bfv8 u1 = *(const bfv8*)(TW + rwa * 72 + 32 + g * 8);
      c0w = __builtin_amdgcn_mfma_f32_16x16x32_bf16(qf0, u0, c0w, 0, 0, 0);
      c0w = __builtin_amdgcn_mfma_f32_16x16x32_bf16(qf1, u1, c0w, 0, 0, 0);
      bfv8 u2 = *(const bfv8*)(TW + rwb * 72 + g * 8);
      bfv8 u3 = *(const bfv8*)(TW + rwb * 72 + 32 + g * 8);
      c1w = __builtin_amdgcn_mfma_f32_16x16x32_bf16(qf0, u2, c1w, 0, 0, 0);
      c1w = __builtin_amdgcn_mfma_f32_16x16x32_bf16(qf1, u3, c1w, 0, 0, 0);
    }

    // transpose rel values (x8, bf16) into A-fragment layout via wave-private LDS.
#pragma unroll
    for (int r = 0; r < 4; r++) {
      int row = g * 4 + r;
      int qq = q0 + row;
      int hqr = qq / 14;
      int wq_r = qq - hqr * 14;
      if (q15 < 10) AWw[row * 40 + 30 + q15] = 0;   // pad ch30..39
      float rh = ((hqr == hq1) ? c1h[r] : c0h[r]) * 8.0f;
      AWw[row * 40 + q15] = (q15 <= 13) ? f2bf(rh) : (u16)0;
      int w0p = wq_r + 13 - q15;
      if (w0p >= 0 && w0p <= 13) AWw[row * 40 + 16 + w0p] = f2bf(c0w[r] * 8.0f);
      int w1p = wq_r - 3 - q15;
      if (w1p >= 0 && w1p <= 13) AWw[row * 40 + 16 + w1p] = f2bf(c1w[r] * 8.0f);
    }
    bfv8 qaug = *(const bfv8*)(AWw + q15 * 40 + g * 8);

    // Fused QK^T + bias + single-pass softmax (constant -4 shift; logits bounded)
    float den[4] = {0.f, 0.f, 0.f, 0.f};
#pragma unroll
    for (int t = 0; t < 13; t++) {
      const u16* kr = Klds + (t * 16 + q15) * 64;
      bfv8 kb0 = *(const bfv8*)(kr + ko0);
      bfv8 kb1 = *(const bfv8*)(kr + ko1);
      bfv8 ib = *(const bfv8*)(IndK + (t * 16 + q15) * 40 + g * 8);
      __builtin_amdgcn_s_setprio(1);
      f32x4 a0 = __builtin_amdgcn_mfma_f32_16x16x32_bf16(qaug, ib, zero, 0, 0, 0);
      f32x4 a1 = __builtin_amdgcn_mfma_f32_16x16x32_bf16(qf0, kb0, a0, 0, 0, 0);
      f32x4 st = __builtin_amdgcn_mfma_f32_16x16x32_bf16(qf1, kb1, a1, 0, 0, 0);
      __builtin_amdgcn_s_setprio(0);
#pragma unroll
      for (int r = 0; r < 4; r++) {
        // exp2((st*0.125 - 4) * log2e) folded to one fma: st*0.18033688 - 5.7707802
        float p = (t == 12 && q15 >= 4) ? 0.f : exp2f(st[r] * 0.18033688f - 5.7707802f);
        den[r] += p;
        Pw[(g * 4 + r) * 232 + t * 16 + q15] = f2bf(p);
      }
    }
#pragma unroll
    for (int r = 0; r < 4; r++) {
      den[r] += __shfl_xor(den[r], 1);
      den[r] += __shfl_xor(den[r], 2);
      den[r] += __shfl_xor(den[r], 4);
      den[r] += __shfl_xor(den[r], 8);
    }

    // PV: out[q][n] over 7 k-steps of 32
    f32x4 o[4] = {zero, zero, zero, zero};
    __builtin_amdgcn_s_setprio(1);
#pragma unroll
    for (int ks = 0; ks < 7; ks++) {
      bfv8 pa = *(const bfv8*)(Pw + q15 * 232 + ks * 32 + g * 8);
#pragma unroll
      for (int nt = 0; nt < 4; nt++) {
        int n = nt * 16 + q15;
        int blk = ((ks * 4 + g) ^ (n & 7) ^ (n >> 3));
        bfv8 vb = *(const bfv8*)(VT + n * 256 + blk * 8);
        o[nt] = __builtin_amdgcn_mfma_f32_16x16x32_bf16(pa, vb, o[nt], 0, 0, 0);
      }
    }
    __builtin_amdgcn_s_setprio(0);

    float inv[4];
#pragma unroll
    for (int r = 0; r < 4; r++) inv[r] = 1.0f / den[r];
#pragma unroll
    for (int nt = 0; nt < 4; nt++)
#pragma unroll
      for (int r = 0; r < 4; r++) {
        int s_ = q0 + g * 4 + r;
        if (s_ < 196) AO[((long)(b * 196 + s_)) * 768 + nh * 64 + nt * 16 + q15] = f2bf(o[nt][r] * inv[r]);
      }
  }
}

// ---------------- launch ----------------
#define GEMM_LDS 131072

extern "C" void kernel_launch(void* const* d_in, const int* in_sizes, int n_in,
                              void* d_out, int out_size, void* d_ws, size_t ws_size,
                              hipStream_t stream) {
  const float* hs = (const float*)d_in[0];
  const float* qkvw = (const float*)d_in[1];
  const float* qkvb = (const float*)d_in[2];
  const float* projw = (const float*)d_in[3];
  const float* projb = (const float*)d_in[4];
  const float* rph = (const float*)d_in[5];
  const float* rpw = (const float*)d_in[6];

  char* ws = (char*)d_ws;
  u16* Xb = (u16*)ws;                        // 120,422,400 B (reused as attention output)
  u16* Wq = (u16*)(ws + 120422400);          // 3,538,944 B
  u16* Wp = (u16*)(ws + 123961344);          // 1,179,648 B
  u16* Qb = (u16*)(ws + 125140992);          // 120,422,400 B
  u16* Kb = (u16*)(ws + 245563392);          // 120,422,400 B
  u16* Vb = (u16*)(ws + 365985792);          // 120,422,400 B
  u16* AO = Xb;

  cvt_f32_bf16<<<2048, 256, 0, stream>>>(hs, Xb, 7526400);
  cvt_f32_bf16<<<864, 256, 0, stream>>>(qkvw, Wq, 221184);
  cvt_f32_bf16<<<288, 256, 0, stream>>>(projw, Wp, 73728);

  hipFuncSetAttribute((const void*)qkv_gemm, hipFuncAttributeMaxDynamicSharedMemorySize, GEMM_LDS);
  qkv_gemm<<<2763, 512, GEMM_LDS, stream>>>(Xb, Wq, qkvb, Qb, Kb, Vb);

  hipFuncSetAttribute((const void*)attn_kernel, hipFuncAttributeMaxDynamicSharedMemorySize, SMEM_SZ);
  attn_kernel<<<4800, 512, SMEM_SZ, stream>>>(Qb, Kb, Vb, rph, rpw, AO);

  hipFuncSetAttribute((const void*)proj_gemm, hipFuncAttributeMaxDynamicSharedMemorySize, GEMM_LDS);
  proj_gemm<<<921, 512, GEMM_LDS, stream>>>(AO, Wp, projb, (float*)d_out);
}

// Round 3
// 821.515 us; speedup vs baseline: 1.2187x; 1.0291x over previous
//
#include <hip/hip_runtime.h>
#include <hip/hip_bf16.h>

typedef __bf16 bfv8 __attribute__((ext_vector_type(8)));
typedef float f32x4 __attribute__((ext_vector_type(4)));
typedef unsigned short u16;
typedef unsigned int u32;

#define MT 78400   // total tokens = 400*196

#define SBAR() __builtin_amdgcn_s_barrier()
#define VMCNT(n) asm volatile("s_waitcnt vmcnt(" #n ")" ::: "memory")

__device__ __forceinline__ u16 f2bf(float f) {
  u32 x = __float_as_uint(f);
  return (u16)((x + 0x7FFFu + ((x >> 16) & 1u)) >> 16);
}

__device__ __forceinline__ void gld16(const void* g, void* l) {
  __builtin_amdgcn_global_load_lds((const __attribute__((address_space(1))) void*)g,
                                   (__attribute__((address_space(3))) void*)l, 16, 0, 0);
}

// ---------------- fp32 -> bf16 convert ----------------
__global__ __launch_bounds__(256) void cvt_f32_bf16(const float* __restrict__ src,
                                                    u16* __restrict__ dst, int n8) {
  int stride = gridDim.x * 256;
  for (int i = blockIdx.x * 256 + threadIdx.x; i < n8; i += stride) {
    const float4* s = (const float4*)(src + (long)i * 8);
    float4 a = s[0], b = s[1];
    u32 p0 = f2bf(a.x) | ((u32)f2bf(a.y) << 16);
    u32 p1 = f2bf(a.z) | ((u32)f2bf(a.w) << 16);
    u32 p2 = f2bf(b.x) | ((u32)f2bf(b.y) << 16);
    u32 p3 = f2bf(b.z) | ((u32)f2bf(b.w) << 16);
    uint4 o = {p0, p1, p2, p3};
    *(uint4*)(dst + (long)i * 8) = o;
  }
}

// ================= 256x256 / BK=64 / 8-wave GEMM core, reg-double-buffered =================
// Same schedule as round 2 (verified passing); round 3 change: ALL staging global
// addresses (clamp, *768, swizzle XOR, base adds) hoisted out of the K-loop into 8
// per-thread pointers; per stage op = pointer + kt*64. LDS dests via tid*8 base.
// Swizzle: 16B slot s' = s ^ (row&7), pre-swizzled global source, same XOR on reads.

__device__ __forceinline__ void gemm256_main(const u16* __restrict__ A, const u16* __restrict__ W,
                                             u16* SH, int m0, int n0, int tid,
                                             f32x4 (&acc)[8][4]) {
  const int lane = tid & 63;
  const int q15 = lane & 15, g = lane >> 4;
  const int wid = tid >> 6;
  const int wm = wid >> 2, wn = wid & 3;   // 2 x 4 waves; per-wave C = 128 x 64
  const int x0 = (g ^ (q15 & 7)) << 3;     // swizzled u16 offset of ksub0 (ksub1 = x0^32)
  const int arow0 = wm * 128 + q15;
  const int brow0 = wn * 64 + q15;

  // ---- hoisted staging sources: chunk i covers row r0+64*i of half h (row&7 invariant) ----
  const int r0 = tid >> 3;
  const int gc0 = ((tid & 7) ^ (r0 & 7)) << 3;   // u16 offset, pre-swizzled
  int ra00 = m0 + r0;       if (ra00 > MT - 1) ra00 = MT - 1;
  int ra10 = m0 + 64 + r0;  if (ra10 > MT - 1) ra10 = MT - 1;
  int ra01 = m0 + 128 + r0; if (ra01 > MT - 1) ra01 = MT - 1;
  int ra11 = m0 + 192 + r0; if (ra11 > MT - 1) ra11 = MT - 1;
  const u16* aS00 = A + (long)ra00 * 768 + gc0;
  const u16* aS10 = A + (long)ra10 * 768 + gc0;
  const u16* aS01 = A + (long)ra01 * 768 + gc0;
  const u16* aS11 = A + (long)ra11 * 768 + gc0;
  const u16* bS00 = W + (long)(n0 + r0) * 768 + gc0;
  const u16* bS10 = W + (long)(n0 + 64 + r0) * 768 + gc0;
  const u16* bS01 = W + (long)(n0 + 128 + r0) * 768 + gc0;
  const u16* bS11 = W + (long)(n0 + 192 + r0) * 768 + gc0;
  u16* dA = SH + tid * 8;                  // + sl*32768 + h*8192 (+4096 chunk1)
  u16* dB = dA + 16384;

  auto STGA = [&](int sl, const u16* p0, const u16* p1, int hoff, int kt) {
    u16* d = dA + sl * 32768 + hoff;
    gld16(p0 + kt * 64, d);
    gld16(p1 + kt * 64, d + 4096);
  };
  auto STGB = [&](int sl, const u16* p0, const u16* p1, int hoff, int kt) {
    u16* d = dB + sl * 32768 + hoff;
    gld16(p0 + kt * 64, d);
    gld16(p1 + kt * 64, d + 4096);
  };

  bfv8 b0[4], b1[4];
  bfv8 aX0[2], aX1[2], aY0[2], aY1[2];

  // prologue stages: B0h0,B0h1,A0h0,A0h1,B1h0,B1h1,A1h0 (14 loads)
  STGB(0, bS00, bS10, 0, 0); STGB(0, bS01, bS11, 8192, 0);
  STGA(0, aS00, aS10, 0, 0); STGA(0, aS01, aS11, 8192, 0);
  STGB(1, bS00, bS10, 0, 1); STGB(1, bS01, bS11, 8192, 1);
  STGA(1, aS00, aS10, 0, 1);
  VMCNT(4);                                // B0,A0,B1h0 landed; A1h0,B1h1 in flight
  SBAR();
  {
    const u16* Sb = SH + 16384;            // B(0)
#pragma unroll
    for (int ni = 0; ni < 4; ++ni) {
      const u16* bp = Sb + (brow0 + ni * 16) * 64;
      b0[ni] = *(const bfv8*)(bp + x0);
      b1[ni] = *(const bfv8*)(bp + (x0 ^ 32));
    }
#pragma unroll
    for (int m2 = 0; m2 < 2; ++m2) {       // A(0) quadrant 0 -> set X
      const u16* ap = SH + (arow0 + m2 * 16) * 64;
      aX0[m2] = *(const bfv8*)(ap + x0);
      aX1[m2] = *(const bfv8*)(ap + (x0 ^ 32));
    }
  }

  for (int u = 0; u < 12; ++u) {
    const int sl = u & 1;
    const u16* Sa = SH + sl * 32768;
    const u16* San = SH + (sl ^ 1) * 32768;
    const u16* Sbn = San + 16384;
    const int kn1 = (u + 1 < 12) ? u + 1 : 11;
    const int kn2 = (u + 2 < 12) ? u + 2 : 11;

    // ---- q0: MFMA quad0 (X) ; barrier ; read quad1->Y ; stage A(u+1)h1 ----
    __builtin_amdgcn_s_setprio(1);
#pragma unroll
    for (int m2 = 0; m2 < 2; ++m2)
#pragma unroll
      for (int ni = 0; ni < 4; ++ni)
        acc[m2][ni] = __builtin_amdgcn_mfma_f32_16x16x32_bf16(aX0[m2], b0[ni], acc[m2][ni], 0, 0, 0);
#pragma unroll
    for (int m2 = 0; m2 < 2; ++m2)
#pragma unroll
      for (int ni = 0; ni < 4; ++ni)
        acc[m2][ni] = __builtin_amdgcn_mfma_f32_16x16x32_bf16(aX1[m2], b1[ni], acc[m2][ni], 0, 0, 0);
    __builtin_amdgcn_s_setprio(0);
    SBAR();
#pragma unroll
    for (int m2 = 0; m2 < 2; ++m2) {
      const u16* ap = Sa + (arow0 + (2 + m2) * 16) * 64;
      aY0[m2] = *(const bfv8*)(ap + x0);
      aY1[m2] = *(const bfv8*)(ap + (x0 ^ 32));
    }
    STGA(sl ^ 1, aS01, aS11, 8192, kn1);

    // ---- q1: MFMA quad1 (Y) ; barrier ; read quad2->X ; stage B(u+2)h0 ----
    __builtin_amdgcn_s_setprio(1);
#pragma unroll
    for (int m2 = 0; m2 < 2; ++m2)
#pragma unroll
      for (int ni = 0; ni < 4; ++ni)
        acc[2 + m2][ni] = __builtin_amdgcn_mfma_f32_16x16x32_bf16(aY0[m2], b0[ni], acc[2 + m2][ni], 0, 0, 0);
#pragma unroll
    for (int m2 = 0; m2 < 2; ++m2)
#pragma unroll
      for (int ni = 0; ni < 4; ++ni)
        acc[2 + m2][ni] = __builtin_amdgcn_mfma_f32_16x16x32_bf16(aY1[m2], b1[ni], acc[2 + m2][ni], 0, 0, 0);
    __builtin_amdgcn_s_setprio(0);
    SBAR();
#pragma unroll
    for (int m2 = 0; m2 < 2; ++m2) {
      const u16* ap = Sa + (arow0 + (4 + m2) * 16) * 64;
      aX0[m2] = *(const bfv8*)(ap + x0);
      aX1[m2] = *(const bfv8*)(ap + (x0 ^ 32));
    }
    STGB(sl, bS00, bS10, 0, kn2);

    // ---- q2: MFMA quad2 (X) ; barrier ; read quad3->Y ; stage B(u+2)h1 ----
    __builtin_amdgcn_s_setprio(1);
#pragma unroll
    for (int m2 = 0; m2 < 2; ++m2)
#pragma unroll
      for (int ni = 0; ni < 4; ++ni)
        acc[4 + m2][ni] = __builtin_amdgcn_mfma_f32_16x16x32_bf16(aX0[m2], b0[ni], acc[4 + m2][ni], 0, 0, 0);
#pragma unroll
    for (int m2 = 0; m2 < 2; ++m2)
#pragma unroll
      for (int ni = 0; ni < 4; ++ni)
        acc[4 + m2][ni] = __builtin_amdgcn_mfma_f32_16x16x32_bf16(aX1[m2], b1[ni], acc[4 + m2][ni], 0, 0, 0);
    __builtin_amdgcn_s_setprio(0);
    SBAR();
#pragma unroll
    for (int m2 = 0; m2 < 2; ++m2) {
      const u16* ap = Sa + (arow0 + (6 + m2) * 16) * 64;
      aY0[m2] = *(const bfv8*)(ap + x0);
      aY1[m2] = *(const bfv8*)(ap + (x0 ^ 32));
    }
    STGB(sl, bS01, bS11, 8192, kn2);

    // ---- q3: MFMA quad3 (Y) ; vmcnt(4) ; barrier ; read nextB+quad0->X ; stage A(u+2)h0 ----
    __builtin_amdgcn_s_setprio(1);
#pragma unroll
    for (int m2 = 0; m2 < 2; ++m2)
#pragma unroll
      for (int ni = 0; ni < 4; ++ni)
        acc[6 + m2][ni] = __builtin_amdgcn_mfma_f32_16x16x32_bf16(aY0[m2], b0[ni], acc[6 + m2][ni], 0, 0, 0);
#pragma unroll
    for (int m2 = 0; m2 < 2; ++m2)
#pragma unroll
      for (int ni = 0; ni < 4; ++ni)
        acc[6 + m2][ni] = __builtin_amdgcn_mfma_f32_16x16x32_bf16(aY1[m2], b1[ni], acc[6 + m2][ni], 0, 0, 0);
    __builtin_amdgcn_s_setprio(0);
    VMCNT(4);                    // completes B(u+1)+A(u+1); leaves B(u+2) in flight
    SBAR();
    if (u < 11) {
#pragma unroll
      for (int ni = 0; ni < 4; ++ni) {
        const u16* bp = Sbn + (brow0 + ni * 16) * 64;
        b0[ni] = *(const bfv8*)(bp + x0);
        b1[ni] = *(const bfv8*)(bp + (x0 ^ 32));
      }
#pragma unroll
      for (int m2 = 0; m2 < 2; ++m2) {
        const u16* ap = San + (arow0 + m2 * 16) * 64;
        aX0[m2] = *(const bfv8*)(ap + x0);
        aX1[m2] = *(const bfv8*)(ap + (x0 ^ 32));
      }
    }
    STGA(sl, aS00, aS10, 0, kn2);
  }
  VMCNT(0);                      // drain dummy tail stages before LDS reuse / exit
}

// ---------------- QKV GEMM: 256x256 ----------------
// grid = 307 x 9 = 2763; bijective XCD chunking (q=345, r=3).
__global__ __launch_bounds__(512, 2) void qkv_gemm(const u16* __restrict__ A, const u16* __restrict__ W,
                                                   const float* __restrict__ bias,
                                                   u16* __restrict__ Qo, u16* __restrict__ Ko,
                                                   u16* __restrict__ Vo) {
  extern __shared__ u16 SH[];
  const int tid = threadIdx.x;
  const int orig = blockIdx.x;
  const int xcd = orig & 7, ii = orig >> 3;
  const int wg = (xcd < 3 ? xcd * 346 : 1038 + (xcd - 3) * 345) + ii;
  const int mt = wg / 9, nt = wg - mt * 9;
  const int m0 = mt * 256, n0 = nt * 256;

  f32x4 acc[8][4];
#pragma unroll
  for (int i = 0; i < 8; ++i)
#pragma unroll
    for (int j = 0; j < 4; ++j) acc[i][j] = (f32x4){0.f, 0.f, 0.f, 0.f};

  gemm256_main(A, W, SH, m0, n0, tid, acc);

  const int lane = tid & 63, q15 = lane & 15, g = lane >> 4;
  const int wid = tid >> 6, wm = wid >> 2, wn = wid & 3;
  __syncthreads();                          // all waves done with SH
  const int sel = nt / 3;                   // N-tiles 0-2 -> Q, 3-5 -> K, 6-8 -> V
  u16* dst = (sel == 0) ? Qo : (sel == 1) ? Ko : Vo;
  const int ntr = nt - sel * 3;
  u16* Cs = SH;                             // [128][264]

#pragma unroll
  for (int h = 0; h < 2; ++h) {
    if (wm == h) {
#pragma unroll
      for (int ni = 0; ni < 4; ++ni) {
        int col = wn * 64 + ni * 16 + q15;
        float bb = bias[n0 + col];
#pragma unroll
        for (int mi = 0; mi < 8; ++mi)
#pragma unroll
          for (int r = 0; r < 4; ++r)
            Cs[(mi * 16 + g * 4 + r) * 264 + col] = f2bf(acc[mi][ni][r] + bb);
      }
    }
    __syncthreads();
#pragma unroll
    for (int j = 0; j < 8; ++j) {
      int idx = tid + 512 * j;
      int row = idx >> 5, cc = idx & 31;
      int m = m0 + h * 128 + row;
      if (m < MT) {
        int b = m / 196, s = m - b * 196;
        int nh = ntr * 4 + (cc >> 3);
        int hd0 = (cc & 7) * 8;
        uint4 v = *(const uint4*)(Cs + row * 264 + cc * 8);
        *(uint4*)(dst + (long)b * 150528 + (long)s * 64 + nh * 12544 + hd0) = v;
      }
    }
    if (h == 0) __syncthreads();
  }
}

// ---------------- Proj GEMM: 256x256, f32 output ----------------
// grid = 307 x 3 = 921; bijective XCD chunking (q=115, r=1).
__global__ __launch_bounds__(512, 2) void proj_gemm(const u16* __restrict__ A, const u16* __restrict__ W,
                                                    const float* __restrict__ bias,
                                                    float* __restrict__ out) {
  extern __shared__ u16 SH[];
  const int tid = threadIdx.x;
  const int orig = blockIdx.x;
  const int xcd = orig & 7, ii = orig >> 3;
  const int wg = (xcd < 1 ? xcd * 116 : 116 + (xcd - 1) * 115) + ii;
  const int mt = wg / 3, nt = wg - mt * 3;
  const int m0 = mt * 256, n0 = nt * 256;

  f32x4 acc[8][4];
#pragma unroll
  for (int i = 0; i < 8; ++i)
#pragma unroll
    for (int j = 0; j < 4; ++j) acc[i][j] = (f32x4){0.f, 0.f, 0.f, 0.f};

  gemm256_main(A, W, SH, m0, n0, tid, acc);

  const int lane = tid & 63, q15 = lane & 15, g = lane >> 4;
  const int wid = tid >> 6, wm = wid >> 2, wn = wid & 3;

#pragma unroll
  for (int ni = 0; ni < 4; ++ni) {
    int n = n0 + wn * 64 + ni * 16 + q15;
    float bb = bias[n];
#pragma unroll
    for (int mi = 0; mi < 8; ++mi)
#pragma unroll
      for (int r = 0; r < 4; ++r) {
        int m = m0 + wm * 128 + mi * 16 + g * 4 + r;
        if (m < MT) out[(long)m * 768 + n] = acc[mi][ni][r] + bb;
      }
  }
}

// ---------------- fused rel-pos attention, one block per (b,nh), 8 waves ----------------
// Round 3: SWAPPED QK^T (mfma(K,Q) — identical register data, swapped operand slots):
// lane now holds S[q=q15][k=t*16+g*4+r] -> P-store = 2x v_cvt_pk_bf16_f32 + one
// ds_write_b64 (was 4x f2bf + 4 scalar writes); den is one scalar (2 xor-shuffles);
// tail mask (t==12 && g>0); inv redistributed to C-layout rows via 4 bpermutes.
#define KLDS_OFF 0          // 208*64*2   = 26624
#define INDK_OFF 26624      // 208*40*2   = 16640
#define VT_OFF   43264      // 64*256*2   = 32768
#define TH_OFF   76032      // 27*72*2    = 3888
#define TW_OFF   79920      // 3888
#define AW_OFF   83808      // 8*16*40*2  = 10240
#define P_OFF    94048      // 8*16*232*2 = 59392
#define SMEM_SZ  153440

__global__ __launch_bounds__(512, 2) void attn_kernel(const u16* __restrict__ Q, const u16* __restrict__ K,
                                                      const u16* __restrict__ V,
                                                      const float* __restrict__ rph, const float* __restrict__ rpw,
                                                      u16* __restrict__ AO) {
  extern __shared__ char smem[];
  u16* Klds = (u16*)(smem + KLDS_OFF);
  u16* IndK = (u16*)(smem + INDK_OFF);
  u16* VT = (u16*)(smem + VT_OFF);
  u16* TH = (u16*)(smem + TH_OFF);
  u16* TW = (u16*)(smem + TW_OFF);
  const int tid = threadIdx.x, lane = tid & 63, wid = tid >> 6;
  const int q15 = lane & 15, g = lane >> 4;
  const int bnh = blockIdx.x;
  const int b = bnh / 12, nh = bnh - b * 12;
  const u16* Qg = Q + bnh * 12544;
  const u16* Kg = K + bnh * 12544;
  const u16* Vg = V + bnh * 12544;
  u16* Pw = (u16*)(smem + P_OFF) + wid * 16 * 232;
  u16* AWw = (u16*)(smem + AW_OFF) + wid * 16 * 40;

  // stage K rows 0..195, stride 64, chunk-XOR swizzle via pre-swizzled source
  for (int c = tid; c < 1568; c += 512) {
    int krow = c >> 3, part = c & 7;
    gld16(Kg + krow * 64 + ((part ^ (krow & 7)) << 3), Klds + c * 8);
  }
  // static indicator block: one-hot (bf16 1.0 = 0x3F80) at hk and 16+wk
  for (int i = tid; i < 208 * 40; i += 512) {
    int k = i / 40, j = i - (i / 40) * 40;
    int hk = k / 14, wk = k - hk * 14;
    IndK[i] = (j == hk || j == 16 + wk) ? 0x3F80 : 0;
  }
  // stage V transposed + swizzled; zero-pad k>=196
  for (int idx = tid; idx < 1792; idx += 512) {
    int k = idx >> 3, nb = idx & 7;
    u32 w0 = 0, w1 = 0, w2 = 0, w3 = 0;
    if (k < 196) {
      uint4 t = *(const uint4*)(Vg + k * 64 + nb * 8);
      w0 = t.x; w1 = t.y; w2 = t.z; w3 = t.w;
    }
    u32 wv[4] = {w0, w1, w2, w3};
#pragma unroll
    for (int j = 0; j < 8; j++) {
      int n = nb * 8 + j;
      u16 val = (u16)(wv[j >> 1] >> ((j & 1) * 16));
      int blk = (k >> 3) ^ (n & 7) ^ (n >> 3);
      VT[n * 256 + blk * 8 + (k & 7)] = val;
    }
  }
  // stage rel-pos tables as bf16
  for (int i = tid; i < 27 * 64; i += 512) {
    int r = i >> 6, cc = i & 63;
    TH[r * 72 + cc] = f2bf(rph[i]);
    TW[r * 72 + cc] = f2bf(rpw[i]);
  }
  // zero own wave's P pad columns [208..231]
  for (int i = lane; i < 16 * 24; i += 64) Pw[(i / 24) * 232 + 208 + (i % 24)] = 0;
  __syncthreads();

  const int ksw = q15 & 7;
  const int ko0 = (g ^ ksw) << 3;          // swizzled chunk offsets for K reads
  const int ko1 = ((g + 4) ^ ksw) << 3;

  const f32x4 zero = {0.f, 0.f, 0.f, 0.f};
  for (int qt = wid; qt < 13; qt += 8) {
    const int q0 = qt * 16;
    int qrow = q0 + q15; if (qrow > 195) qrow = 195;
    bfv8 qf0 = *(const bfv8*)(Qg + qrow * 64 + g * 8);
    bfv8 qf1 = *(const bfv8*)(Qg + qrow * 64 + 32 + g * 8);

    // rel_h (two hq variants) and rel_w over d = wq-wk+13 (two d-tiles), via MFMA
    int hq0 = q0 / 14, hq1 = (q0 + 15) / 14;
    int rha = hq0 + 13 - q15; rha = rha < 0 ? 0 : (rha > 26 ? 26 : rha);
    int rhb = hq1 + 13 - q15; rhb = rhb < 0 ? 0 : (rhb > 26 ? 26 : rhb);
    int rwa = q15;
    int rwb = 16 + q15; if (rwb > 26) rwb = 26;
    f32x4 c0h = zero, c1h = zero, c0w = zero, c1w = zero;
    {
      bfv8 t0 = *(const bfv8*)(TH + rha * 72 + g * 8);
      bfv8 t1 = *(const bfv8*)(TH + rha * 72 + 32 + g * 8);
      c0h = __builtin_amdgcn_mfma_f32_16x16x32_bf16(qf0, t0, c0h, 0, 0, 0);
      c0h = __builtin_amdgcn_mfma_f32_16x16x32_bf16(qf1, t1, c0h, 0, 0, 0);
      bfv8 t2 = *(const bfv8*)(TH + rhb * 72 + g * 8);
      bfv8 t3 = *(const bfv8*)(TH + rhb * 72 + 32 + g * 8);
      c1h = __builtin_amdgcn_mfma_f32_16x16x32_bf16(qf0, t2, c1h, 0, 0, 0);
      c1h = __builtin_amdgcn_mfma_f32_16x16x32_bf16(qf1, t3, c1h, 0, 0, 0);
      bfv8 u0 = *(const bfv8*)(TW + rwa * 72 + g * 8);
      bfv8 u1 = *(const bfv8*)(TW + rwa * 72 + 32 + g * 8);
      c0w = __builtin_amdgcn_mfma_f32_16x16x32_bf16(qf0, u0, c0w, 0, 0, 0);
      c0w = __builtin_amdgcn_mfma_f32_16x16x32_bf16(qf1, u1, c0w, 0, 0, 0);
      bfv8 u2 = *(const bfv8*)(TW + rwb * 72 + g * 8);
      bfv8 u3 = *(const bfv8*)(TW + rwb * 72 + 32 + g * 8);
      c0w = c0w;
      c1w = __builtin_amdgcn_mfma_f32_16x16x32_bf16(qf0, u2, c1w, 0, 0, 0);
      c1w = __builtin_amdgcn_mfma_f32_16x16x32_bf16(qf1, u3, c1w, 0, 0, 0);
    }

    // transpose rel values (x8, bf16) into A-fragment layout via wave-private LDS.
#pragma unroll
    for (int r = 0; r < 4; r++) {
      int row = g * 4 + r;
      int qq = q0 + row;
      int hqr = qq / 14;
      int wq_r = qq - hqr * 14;
      if (q15 < 10) AWw[row * 40 + 30 + q15] = 0;   // pad ch30..39
      float rh = ((hqr == hq1) ? c1h[r] : c0h[r]) * 8.0f;
      AWw[row * 40 + q15] = (q15 <= 13) ? f2bf(rh) : (u16)0;
      int w0p = wq_r + 13 - q15;
      if (w0p >= 0 && w0p <= 13) AWw[row * 40 + 16 + w0p] = f2bf(c0w[r] * 8.0f);
      int w1p = wq_r - 3 - q15;
      if (w1p >= 0 && w1p <= 13) AWw[row * 40 + 16 + w1p] = f2bf(c1w[r] * 8.0f);
    }
    bfv8 qaug = *(const bfv8*)(AWw + q15 * 40 + g * 8);

    // Fused QK^T (SWAPPED operands -> S^T) + bias + single-pass softmax.
    // Lane holds S[q=q15][k=t*16+g*4+r]: 4 consecutive k -> packed b64 P-store.
    float den = 0.f;
#pragma unroll
    for (int t = 0; t < 13; t++) {
      const u16* kr = Klds + (t * 16 + q15) * 64;
      bfv8 kb0 = *(const bfv8*)(kr + ko0);
      bfv8 kb1 = *(const bfv8*)(kr + ko1);
      bfv8 ib = *(const bfv8*)(IndK + (t * 16 + q15) * 40 + g * 8);
      __builtin_amdgcn_s_setprio(1);
      f32x4 a0 = __builtin_amdgcn_mfma_f32_16x16x32_bf16(ib, qaug, zero, 0, 0, 0);
      f32x4 a1 = __builtin_amdgcn_mfma_f32_16x16x32_bf16(kb0, qf0, a0, 0, 0, 0);
      f32x4 st = __builtin_amdgcn_mfma_f32_16x16x32_bf16(kb1, qf1, a1, 0, 0, 0);
      __builtin_amdgcn_s_setprio(0);
      float p0 = (t == 12 && g > 0) ? 0.f : exp2f(st[0] * 0.18033688f - 5.7707802f);
      float p1 = (t == 12 && g > 0) ? 0.f : exp2f(st[1] * 0.18033688f - 5.7707802f);
      float p2 = (t == 12 && g > 0) ? 0.f : exp2f(st[2] * 0.18033688f - 5.7707802f);
      float p3 = (t == 12 && g > 0) ? 0.f : exp2f(st[3] * 0.18033688f - 5.7707802f);
      den += (p0 + p1) + (p2 + p3);
      u32 lo, hi;
      asm("v_cvt_pk_bf16_f32 %0, %1, %2" : "=v"(lo) : "v"(p0), "v"(p1));
      asm("v_cvt_pk_bf16_f32 %0, %1, %2" : "=v"(hi) : "v"(p2), "v"(p3));
      uint2 pk = {lo, hi};
      *(uint2*)(Pw + q15 * 232 + t * 16 + g * 4) = pk;
    }
    den += __shfl_xor(den, 16);
    den += __shfl_xor(den, 32);
    float inv = 1.0f / den;
    float invr[4];
#pragma unroll
    for (int r = 0; r < 4; r++) invr[r] = __shfl(inv, g * 4 + r);

    // PV: out[q][n] over 7 k-steps of 32
    f32x4 o[4] = {zero, zero, zero, zero};
    __builtin_amdgcn_s_setprio(1);
#pragma unroll
    for (int ks = 0; ks < 7; ks++) {
      bfv8 pa = *(const bfv8*)(Pw + q15 * 232 + ks * 32 + g * 8);
#pragma unroll
      for (int nt = 0; nt < 4; nt++) {
        int n = nt * 16 + q15;
        int blk = ((ks * 4 + g) ^ (n & 7) ^ (n >> 3));
        bfv8 vb = *(const bfv8*)(VT + n * 256 + blk * 8);
        o[nt] = __builtin_amdgcn_mfma_f32_16x16x32_bf16(pa, vb, o[nt], 0, 0, 0);
      }
    }
    __builtin_amdgcn_s_setprio(0);

#pragma unroll
    for (int nt = 0; nt < 4; nt++)
#pragma unroll
      for (int r = 0; r < 4; r++) {
        int s_ = q0 + g * 4 + r;
        if (s_ < 196) AO[((long)(b * 196 + s_)) * 768 + nh * 64 + nt * 16 + q15] = f2bf(o[nt][r] * invr[r]);
      }
  }
}

// ---------------- launch ----------------
#define GEMM_LDS 131072

extern "C" void kernel_launch(void* const* d_in, const int* in_sizes, int n_in,
                              void* d_out, int out_size, void* d_ws, size_t ws_size,
                              hipStream_t stream) {
  const float* hs = (const float*)d_in[0];
  const float* qkvw = (const float*)d_in[1];
  const float* qkvb = (const float*)d_in[2];
  const float* projw = (const float*)d_in[3];
  const float* projb = (const float*)d_in[4];
  const float* rph = (const float*)d_in[5];
  const float* rpw = (const float*)d_in[6];

  char* ws = (char*)d_ws;
  u16* Xb = (u16*)ws;                        // 120,422,400 B (reused as attention output)
  u16* Wq = (u16*)(ws + 120422400);          // 3,538,944 B
  u16* Wp = (u16*)(ws + 123961344);          // 1,179,648 B
  u16* Qb = (u16*)(ws + 125140992);          // 120,422,400 B
  u16* Kb = (u16*)(ws + 245563392);          // 120,422,400 B
  u16* Vb = (u16*)(ws + 365985792);          // 120,422,400 B
  u16* AO = Xb;

  cvt_f32_bf16<<<2048, 256, 0, stream>>>(hs, Xb, 7526400);
  cvt_f32_bf16<<<864, 256, 0, stream>>>(qkvw, Wq, 221184);
  cvt_f32_bf16<<<288, 256, 0, stream>>>(projw, Wp, 73728);

  hipFuncSetAttribute((const void*)qkv_gemm, hipFuncAttributeMaxDynamicSharedMemorySize, GEMM_LDS);
  qkv_gemm<<<2763, 512, GEMM_LDS, stream>>>(Xb, Wq, qkvb, Qb, Kb, Vb);

  hipFuncSetAttribute((const void*)attn_kernel, hipFuncAttributeMaxDynamicSharedMemorySize, SMEM_SZ);
  attn_kernel<<<4800, 512, SMEM_SZ, stream>>>(Qb, Kb, Vb, rph, rpw, AO);

  hipFuncSetAttribute((const void*)proj_gemm, hipFuncAttributeMaxDynamicSharedMemorySize, GEMM_LDS);
  proj_gemm<<<921, 512, GEMM_LDS, stream>>>(AO, Wp, projb, (float*)d_out);
}